// Round 7
// baseline (945.463 us; speedup 1.0000x reference)
//
#include <hip/hip_runtime.h>
#include <math.h>

// JCPOT Sinkhorn. d_out: [0]=loss, [1..16M]=coupling, [1+16M..]=C.
// Round 7: single kernel per Sinkhorn iteration via vacc-chain + L2 atomics
// (no partial buffer, no vred/vfin launches): 25 -> 14 launches.
// gemm16b / k_prep / final3 skeleton proven in round 6. No global barriers
// (measured 19-34us/sync rounds 3-4). Fallback (tiny ws): round-1 pipeline.

#define N_S 4096
#define N_T 4096
#define DIM 512
#define STAB 1e-8f

typedef _Float16 f16x4 __attribute__((ext_vector_type(4)));
typedef _Float16 f16x8 __attribute__((ext_vector_type(8)));
typedef float f32x4v __attribute__((ext_vector_type(4)));

// ---------- fused: row norms + fp32->fp16 K-tile-blocked convert + scalar init ----------
__global__ __launch_bounds__(256) void k_prep(const float* __restrict__ S, const float* __restrict__ T,
                                              _Float16* __restrict__ Sh2, _Float16* __restrict__ Th2,
                                              float* __restrict__ ns, float* __restrict__ nt,
                                              float* __restrict__ vacc, double* __restrict__ lossd) {
    int t = threadIdx.x, lane = t & 63, wave = t >> 6;
    int wid = blockIdx.x * 4 + wave;               // 0..8191
    const float* src; _Float16* dst; float* ndst; int row;
    if (wid < N_S) { src = S; dst = Sh2; ndst = ns; row = wid; }
    else           { src = T; dst = Th2; ndst = nt; row = wid - N_S; }
    int cb = lane * 8;
    float4 x0 = *(const float4*)(src + (size_t)row * DIM + cb);
    float4 x1 = *(const float4*)(src + (size_t)row * DIM + cb + 4);
    float acc = x0.x*x0.x + x0.y*x0.y + x0.z*x0.z + x0.w*x0.w
              + x1.x*x1.x + x1.y*x1.y + x1.z*x1.z + x1.w*x1.w;
#pragma unroll
    for (int m = 32; m; m >>= 1) acc += __shfl_xor(acc, m);
    if (lane == 0) ndst[row] = acc;
    f16x8 h = { (_Float16)x0.x, (_Float16)x0.y, (_Float16)x0.z, (_Float16)x0.w,
                (_Float16)x1.x, (_Float16)x1.y, (_Float16)x1.z, (_Float16)x1.w };
    *(f16x8*)(dst + ((size_t)(cb >> 5) * 4096 + row) * 32 + (cb & 31)) = h;

    // scalar init (block 0): vacc[0]=1/N_T-STAB (so derived v0==1), vacc[1..10]=0, loss=0
    if (blockIdx.x == 0) {
        for (int idx = t; idx < 11 * 4096; idx += 256)
            vacc[idx] = (idx < 4096) ? (1.0f / N_T - STAB) : 0.0f;
        if (t == 0) *lossd = 0.0;
    }
}

// ---------- GEMM (f16 MFMA, blocked inputs): coalesced C + fused fp16 Kh (round-6 proven) ----------
__global__ __launch_bounds__(256) void k_gemm16b(const _Float16* __restrict__ Sh2,
                                                 const _Float16* __restrict__ Th2,
                                                 const float* __restrict__ ns,
                                                 const float* __restrict__ nt,
                                                 float* __restrict__ outC,
                                                 _Float16* __restrict__ Kh) {
    __shared__ _Float16 As[128 * 40];
    __shared__ _Float16 Bs[128 * 40];
    __shared__ float eps[4][16 * 68];
    int t = threadIdx.x;
    int lane = t & 63, wave = t >> 6;
    int wr = wave >> 1, wc = wave & 1;
    int brow = blockIdx.x * 128, bcol = blockIdx.y * 128;

    f32x4v acc[4][4] = {};

    for (int kt = 0; kt < 16; ++kt) {
        __syncthreads();
        const _Float16* Ab = Sh2 + ((size_t)kt * 4096 + brow) * 32;
        const _Float16* Bb = Th2 + ((size_t)kt * 4096 + bcol) * 32;
#pragma unroll
        for (int w = 0; w < 2; ++w) {
            int e = w * 2048 + t * 8, row = e >> 5, col = e & 31;
            *(f16x8*)(&As[row * 40 + col]) = *(const f16x8*)(Ab + row * 32 + col);
            *(f16x8*)(&Bs[row * 40 + col]) = *(const f16x8*)(Bb + row * 32 + col);
        }
        __syncthreads();

        f16x8 af[4], bf[4];
#pragma unroll
        for (int m = 0; m < 4; ++m)
            af[m] = *(const f16x8*)(&As[(wr * 64 + m * 16 + (lane & 15)) * 40 + (lane >> 4) * 8]);
#pragma unroll
        for (int n = 0; n < 4; ++n)
            bf[n] = *(const f16x8*)(&Bs[(wc * 64 + n * 16 + (lane & 15)) * 40 + (lane >> 4) * 8]);
#pragma unroll
        for (int m = 0; m < 4; ++m)
#pragma unroll
            for (int n = 0; n < 4; ++n)
                acc[m][n] = __builtin_amdgcn_mfma_f32_16x16x32_f16(af[m], bf[n], acc[m][n], 0, 0, 0);
    }

    float* my = &eps[wave][0];
#pragma unroll
    for (int m = 0; m < 4; ++m) {
#pragma unroll
        for (int n = 0; n < 4; ++n)
#pragma unroll
            for (int r = 0; r < 4; ++r)
                my[((lane >> 4) * 4 + r) * 68 + n * 16 + (lane & 15)] = acc[m][n][r];
        __syncthreads();
#pragma unroll
        for (int rep = 0; rep < 4; ++rep) {
            int rr = (lane >> 4) + rep * 4;
            int cc = (lane & 15) * 4;
            float4 d = *(float4*)(my + rr * 68 + cc);
            int i = brow + wr * 64 + m * 16 + rr;
            int j = bcol + wc * 64 + cc;
            float nsi = ns[i];
            float4 nt4 = *(const float4*)(nt + j);
            float4 c4;
            c4.x = sqrtf(fmaxf(nsi + nt4.x - 2.0f * d.x, 0.0f));
            c4.y = sqrtf(fmaxf(nsi + nt4.y - 2.0f * d.y, 0.0f));
            c4.z = sqrtf(fmaxf(nsi + nt4.z - 2.0f * d.z, 0.0f));
            c4.w = sqrtf(fmaxf(nsi + nt4.w - 2.0f * d.w, 0.0f));
            *(float4*)(outC + (size_t)i * N_T + j) = c4;
            f16x4 kh4 = { (_Float16)__expf(c4.x * -0.125f),
                          (_Float16)__expf(c4.y * -0.125f),
                          (_Float16)__expf(c4.z * -0.125f),
                          (_Float16)__expf(c4.w * -0.125f) };
            *(f16x4*)(Kh + (size_t)i * N_T + j) = kh4;
        }
        __syncthreads();
    }
}

// ---------- fused Sinkhorn iteration (single kernel): vacc-chain + atomics ----------
// 512 blocks x 256 thr, 8 rows/block (wave handles 2). Reads vaccPrev (derives v
// inline, hoisted per thread), computes u, accumulates col sums into vaccNext.
__global__ __launch_bounds__(256) void k_sinkA(const _Float16* __restrict__ Kh,
                                               const float* __restrict__ vaccPrev,
                                               float* __restrict__ vaccNext,
                                               float* __restrict__ u_out) {
    __shared__ _Float16 rows[8][4096];   // 64 KB
    __shared__ float u_s[8];
    int t = threadIdx.x, lane = t & 63, w = t >> 6;
    int rowbase = blockIdx.x * 8;

    // hoist v for this lane's 64 columns (8 segments x 8 cols)
    float vf[8][8];
#pragma unroll
    for (int s = 0; s < 8; ++s) {
        int j0 = s * 512 + lane * 8;
        float4 a0 = *(const float4*)(vaccPrev + j0);
        float4 a1 = *(const float4*)(vaccPrev + j0 + 4);
        vf[s][0] = (1.0f / N_T) / (a0.x + STAB);
        vf[s][1] = (1.0f / N_T) / (a0.y + STAB);
        vf[s][2] = (1.0f / N_T) / (a0.z + STAB);
        vf[s][3] = (1.0f / N_T) / (a0.w + STAB);
        vf[s][4] = (1.0f / N_T) / (a1.x + STAB);
        vf[s][5] = (1.0f / N_T) / (a1.y + STAB);
        vf[s][6] = (1.0f / N_T) / (a1.z + STAB);
        vf[s][7] = (1.0f / N_T) / (a1.w + STAB);
    }

#pragma unroll
    for (int rr = 0; rr < 2; ++rr) {
        int ridx = rr * 4 + w;
        int row = rowbase + ridx;
        const _Float16* Kr = Kh + (size_t)row * N_T;
        f16x8 kk[8];
#pragma unroll
        for (int s = 0; s < 8; ++s)
            kk[s] = *(const f16x8*)(Kr + s * 512 + lane * 8);
        float dot = 0.f;
#pragma unroll
        for (int s = 0; s < 8; ++s) {
            *(f16x8*)(&rows[ridx][s * 512 + lane * 8]) = kk[s];
#pragma unroll
            for (int c = 0; c < 8; ++c)
                dot += (float)kk[s][c] * vf[s][c];
        }
#pragma unroll
        for (int m = 32; m; m >>= 1) dot += __shfl_xor(dot, m);
        if (lane == 0) {
            float uv = (1.0f / N_S) / (dot + STAB);
            u_s[ridx] = uv;
            u_out[row] = uv;
        }
    }
    __syncthreads();

    // column partials across the block's 8 rows -> atomic accumulate
#pragma unroll
    for (int s = 0; s < 4; ++s) {
        int j = t * 4 + s * 1024;
        float4 a = {0.f, 0.f, 0.f, 0.f};
#pragma unroll
        for (int r = 0; r < 8; ++r) {
            f16x4 k4 = *(const f16x4*)(&rows[r][j]);
            float uu = u_s[r];
            a.x += uu * (float)k4[0];
            a.y += uu * (float)k4[1];
            a.z += uu * (float)k4[2];
            a.w += uu * (float)k4[3];
        }
        atomicAdd(vaccNext + j + 0, a.x);
        atomicAdd(vaccNext + j + 1, a.y);
        atomicAdd(vaccNext + j + 2, a.z);
        atomicAdd(vaccNext + j + 3, a.w);
    }
}

// ---------- coupling = u*Kh*v + loss; v derived from vacc10; C recovered as -8*ln(Kh) ----------
__global__ __launch_bounds__(256) void k_final3(const _Float16* __restrict__ Kh,
                                                const float* __restrict__ u,
                                                const float* __restrict__ vacc10,
                                                float* __restrict__ W, double* __restrict__ lossd) {
    int t = threadIdx.x, row = blockIdx.x;
    float ui = u[row];
    float lacc = 0.f;
    const float NEG8LN2 = -5.5451774444795623f;    // -8*ln(2)
    const _Float16* Kr = Kh + (size_t)row * N_T;
    float* Wr = W + (size_t)row * N_T;
#pragma unroll
    for (int cc = 0; cc < 4; ++cc) {
        int j = (cc * 256 + t) * 4;
        f16x4 kk = *(const f16x4*)(Kr + j);
        float4 va = *(const float4*)(vacc10 + j);
        float4 v4;
        v4.x = (1.0f / N_T) / (va.x + STAB);
        v4.y = (1.0f / N_T) / (va.y + STAB);
        v4.z = (1.0f / N_T) / (va.z + STAB);
        v4.w = (1.0f / N_T) / (va.w + STAB);
        float kf0 = (float)kk[0], kf1 = (float)kk[1], kf2 = (float)kk[2], kf3 = (float)kk[3];
        float4 w4;
        w4.x = ui * kf0 * v4.x;
        w4.y = ui * kf1 * v4.y;
        w4.z = ui * kf2 * v4.z;
        w4.w = ui * kf3 * v4.w;
        *(float4*)(Wr + j) = w4;
        lacc += w4.x * (NEG8LN2 * __log2f(kf0)) + w4.y * (NEG8LN2 * __log2f(kf1))
              + w4.z * (NEG8LN2 * __log2f(kf2)) + w4.w * (NEG8LN2 * __log2f(kf3));
    }
#pragma unroll
    for (int m = 32; m; m >>= 1) lacc += __shfl_xor(lacc, m);
    __shared__ float wsum[4];
    int lane = t & 63, wave = t >> 6;
    if (lane == 0) wsum[wave] = lacc;
    __syncthreads();
    if (t == 0) atomicAdd(lossd, (double)(wsum[0] + wsum[1] + wsum[2] + wsum[3]));
}

__global__ void k_loss(const double* __restrict__ lossd, float* __restrict__ out0) {
    *out0 = (float)(*lossd / ((double)N_S * (double)N_T));
}

// ================= round-1 proven kernels (tiny-ws fallback) =================
__global__ __launch_bounds__(256) void k_norms(const float4* __restrict__ S4,
                                               const float4* __restrict__ T4,
                                               float* __restrict__ ns, float* __restrict__ nt) {
    int t = threadIdx.x;
    int lane = t & 63, wave = t >> 6;
    int wid = blockIdx.x * 4 + wave;
    const float4* src; float* dst; int row;
    if (wid < N_S) { src = S4; dst = ns; row = wid; }
    else           { src = T4; dst = nt; row = wid - N_S; }
    float acc = 0.f;
#pragma unroll
    for (int c = 0; c < 2; ++c) {
        float4 x = src[row * 128 + c * 64 + lane];
        acc += x.x*x.x + x.y*x.y + x.z*x.z + x.w*x.w;
    }
#pragma unroll
    for (int m = 32; m; m >>= 1) acc += __shfl_xor(acc, m);
    if (lane == 0) dst[row] = acc;
}

__global__ void k_init0(float* v, float* vacc, double* lossd) {
    int g = blockIdx.x * 256 + threadIdx.x;
    if (g < N_T) { v[g] = 1.0f; vacc[g] = 0.0f; }
    if (g == 0) *lossd = 0.0;
}

__global__ __launch_bounds__(256) void k_gemm0(const float* __restrict__ S, const float* __restrict__ T,
                                               const float* __restrict__ ns, const float* __restrict__ nt,
                                               float* __restrict__ outK, float* __restrict__ outC) {
    __shared__ _Float16 As[128 * 40];
    __shared__ _Float16 Bs[128 * 40];
    int t = threadIdx.x;
    int lane = t & 63, wave = t >> 6;
    int wr = wave >> 1, wc = wave & 1;
    int brow = blockIdx.x * 128, bcol = blockIdx.y * 128;

    f32x4v acc[4][4] = {};

    for (int kt = 0; kt < DIM; kt += 32) {
        __syncthreads();
#pragma unroll
        for (int w = 0; w < 4; ++w) {
            int e = w * 1024 + t * 4;
            int row = e >> 5, col = e & 31;
            float4 a = *(const float4*)(S + (size_t)(brow + row) * DIM + kt + col);
            f16x4 ah = { (_Float16)a.x, (_Float16)a.y, (_Float16)a.z, (_Float16)a.w };
            *(f16x4*)(&As[row * 40 + col]) = ah;
            float4 b = *(const float4*)(T + (size_t)(bcol + row) * DIM + kt + col);
            f16x4 bh = { (_Float16)b.x, (_Float16)b.y, (_Float16)b.z, (_Float16)b.w };
            *(f16x4*)(&Bs[row * 40 + col]) = bh;
        }
        __syncthreads();

        f16x8 af[4], bf[4];
#pragma unroll
        for (int m = 0; m < 4; ++m)
            af[m] = *(const f16x8*)(&As[(wr * 64 + m * 16 + (lane & 15)) * 40 + (lane >> 4) * 8]);
#pragma unroll
        for (int n = 0; n < 4; ++n)
            bf[n] = *(const f16x8*)(&Bs[(wc * 64 + n * 16 + (lane & 15)) * 40 + (lane >> 4) * 8]);
#pragma unroll
        for (int m = 0; m < 4; ++m)
#pragma unroll
            for (int n = 0; n < 4; ++n)
                acc[m][n] = __builtin_amdgcn_mfma_f32_16x16x32_f16(af[m], bf[n], acc[m][n], 0, 0, 0);
    }

#pragma unroll
    for (int m = 0; m < 4; ++m) {
#pragma unroll
        for (int n = 0; n < 4; ++n) {
#pragma unroll
            for (int r = 0; r < 4; ++r) {
                int i = brow + wr * 64 + m * 16 + (lane >> 4) * 4 + r;
                int j = bcol + wc * 64 + n * 16 + (lane & 15);
                float sq = ns[i] + nt[j] - 2.0f * acc[m][n][r];
                float c = sqrtf(fmaxf(sq, 0.0f));
                size_t idx = (size_t)i * N_T + j;
                outC[idx] = c;
                outK[idx] = __expf(-c * 0.125f);
            }
        }
    }
}

__global__ __launch_bounds__(256) void k_rowmv(const float* __restrict__ Kd,
                                               const float* __restrict__ v, float* __restrict__ u) {
    __shared__ float vl[4096];
    int t = threadIdx.x;
#pragma unroll
    for (int c = 0; c < 16; ++c) vl[c * 256 + t] = v[c * 256 + t];
    __syncthreads();
    int lane = t & 63, wave = t >> 6;
    int row = blockIdx.x * 4 + wave;
    const float* Kr = Kd + (size_t)row * N_T;
    float dot = 0.f;
#pragma unroll 8
    for (int c = 0; c < 64; ++c) {
        int j = c * 64 + lane;
        dot += Kr[j] * vl[j];
    }
#pragma unroll
    for (int m = 32; m; m >>= 1) dot += __shfl_xor(dot, m);
    if (lane == 0) u[row] = (1.0f / N_S) / (dot + STAB);
}

__global__ __launch_bounds__(256) void k_colmv(const float* __restrict__ Kd,
                                               const float* __restrict__ u, float* __restrict__ vacc) {
    __shared__ float ul[64];
    int t = threadIdx.x;
    int rc = blockIdx.y;
    if (t < 64) ul[t] = u[rc * 64 + t];
    __syncthreads();
    int j = blockIdx.x * 256 + t;
    const float* Kp = Kd + (size_t)(rc * 64) * N_T + j;
    float acc = 0.f;
#pragma unroll 8
    for (int r = 0; r < 64; ++r) acc += Kp[(size_t)r * N_T] * ul[r];
    atomicAdd(&vacc[j], acc);
}

__global__ void k_vfin(float* v, float* vacc) {
    int j = blockIdx.x * 256 + threadIdx.x;
    v[j] = (1.0f / N_T) / (vacc[j] + STAB);
    vacc[j] = 0.f;
}

__global__ __launch_bounds__(256) void k_final(float* __restrict__ Kd, const float* __restrict__ Cd,
                                               const float* __restrict__ u, const float* __restrict__ v,
                                               double* __restrict__ lossd) {
    int t = threadIdx.x;
    int row = blockIdx.x;
    float ui = u[row];
    float lacc = 0.f;
#pragma unroll 4
    for (int c = 0; c < 16; ++c) {
        int j = c * 256 + t;
        size_t idx = (size_t)row * N_T + j;
        float w = ui * Kd[idx] * v[j];
        Kd[idx] = w;
        lacc += w * Cd[idx];
    }
#pragma unroll
    for (int m = 32; m; m >>= 1) lacc += __shfl_xor(lacc, m);
    __shared__ float wsum[4];
    int lane = t & 63, wave = t >> 6;
    if (lane == 0) wsum[wave] = lacc;
    __syncthreads();
    if (t == 0) atomicAdd(lossd, (double)(wsum[0] + wsum[1] + wsum[2] + wsum[3]));
}

// =====================================================================
extern "C" void kernel_launch(void* const* d_in, const int* in_sizes, int n_in,
                              void* d_out, int out_size, void* d_ws, size_t ws_size,
                              hipStream_t stream) {
    const float* S = (const float*)d_in[0];
    const float* T = (const float*)d_in[1];
    float* out = (float*)d_out;
    float* outCoup = out + 1;
    float* outC = out + 1 + (size_t)N_S * N_T;

    const size_t MB = 1024 * 1024;
    // main ws layout: Sh2 4MB | Th2 4MB | Kh 32MB | vacc[11][4096] | u | ns | nt | lossd
    const size_t need = 40 * MB + (11 + 3) * 4096 * 4 + 64;

    if (ws_size >= need) {
        char* wsb = (char*)d_ws;
        _Float16* Sh2 = (_Float16*)wsb;                 // 4 MB (K-tile-blocked fp16 S)
        _Float16* Th2 = (_Float16*)(wsb + 4 * MB);      // 4 MB
        _Float16* Kh  = (_Float16*)(wsb + 8 * MB);      // 32 MB
        float* vacc   = (float*)(wsb + 40 * MB);        // [11][4096]
        float* u      = vacc + 11 * 4096;
        float* ns     = u + 4096;
        float* nt     = ns + 4096;
        double* lossd = (double*)(nt + 4096);

        k_prep<<<2048, 256, 0, stream>>>(S, T, Sh2, Th2, ns, nt, vacc, lossd);
        k_gemm16b<<<dim3(32, 32), 256, 0, stream>>>(Sh2, Th2, ns, nt, outC, Kh);
        for (int it = 0; it < 10; ++it)
            k_sinkA<<<512, 256, 0, stream>>>(Kh, vacc + (size_t)it * 4096,
                                             vacc + (size_t)(it + 1) * 4096, u);
        k_final3<<<4096, 256, 0, stream>>>(Kh, u, vacc + 10 * 4096, outCoup, lossd);
        k_loss<<<1, 1, 0, stream>>>(lossd, out);
    } else {
        // tiny-ws: round-1 proven fallback end-to-end (fp32 K staged in coupling slot)
        float* outK = outCoup;
        float* ws   = (float*)d_ws;
        float* ns   = ws;
        float* nt   = ws + 4096;
        float* u    = ws + 8192;
        float* v    = ws + 12288;
        float* vacc = ws + 16384;
        double* lossd = (double*)(ws + 20480);

        k_norms<<<2048, 256, 0, stream>>>((const float4*)S, (const float4*)T, ns, nt);
        k_init0<<<16, 256, 0, stream>>>(v, vacc, lossd);
        k_gemm0<<<dim3(32, 32), 256, 0, stream>>>(S, T, ns, nt, outK, outC);
        for (int it = 0; it < 10; ++it) {
            k_rowmv<<<1024, 256, 0, stream>>>(outK, v, u);
            k_colmv<<<dim3(16, 64), 256, 0, stream>>>(outK, u, vacc);
            k_vfin<<<16, 256, 0, stream>>>(v, vacc);
        }
        k_final<<<4096, 256, 0, stream>>>(outK, outC, u, v, lossd);
        k_loss<<<1, 1, 0, stream>>>(lossd, out);
    }
}